// Round 1
// baseline (364.729 us; speedup 1.0000x reference)
//
#include <hip/hip_runtime.h>
#include <hip/hip_bf16.h>

#define B_  2
#define S_  2048
#define D_  1024
#define H_  16
#define HD_ 64

typedef float  f32x4 __attribute__((ext_vector_type(4)));
typedef __bf16 bf16x8 __attribute__((ext_vector_type(8)));
typedef unsigned short us8 __attribute__((ext_vector_type(8)));

__device__ __forceinline__ unsigned short f2bf(float f) {
    union { float f; unsigned int u; } x; x.f = f;
    unsigned int u = x.u;
    unsigned int r = (u + 0x7FFFu + ((u >> 16) & 1u)) >> 16;
    return (unsigned short)r;
}

// ---------------- fp32 -> bf16 convert ----------------
__global__ __launch_bounds__(256) void cvt_f32_bf16(
    const float* __restrict__ src, unsigned short* __restrict__ dst, int n)
{
    int i = (blockIdx.x * 256 + threadIdx.x) * 4;
    if (i < n) {
        float4 v = *reinterpret_cast<const float4*>(src + i);
        ushort4 o;
        o.x = f2bf(v.x); o.y = f2bf(v.y); o.z = f2bf(v.z); o.w = f2bf(v.w);
        *reinterpret_cast<ushort4*>(dst + i) = o;
    }
}

// ---------------- GEMM: C[m][n] = sum_k A[m,k]*B[n,k] + bias[n] ----------------
// A: [M][K] bf16, B: [N][K] bf16 (i.e. computes A @ B^T), bias fp32.
// 64x64 tile, 4 waves (2x2), BK=64.
template <typename OutT>
__global__ __launch_bounds__(256) void gemm_bt(
    const unsigned short* __restrict__ A,
    const unsigned short* __restrict__ Bm,
    const float* __restrict__ bias,
    OutT* __restrict__ C,
    int M, int N, int K)
{
    __shared__ unsigned short As[64][80];   // +16 pad: 160B stride, 16B-aligned
    __shared__ unsigned short Bs[64][80];
    const int tid  = threadIdx.x;
    const int lane = tid & 63;
    const int w    = tid >> 6;
    const int wm   = w >> 1, wn = w & 1;
    const int m0   = blockIdx.x << 6, n0 = blockIdx.y << 6;
    const int l15  = lane & 15, l4 = lane >> 4;

    f32x4 acc[2][2] = {};

    const int sr = tid >> 2;          // 0..63 row
    const int sc = (tid & 3) << 4;    // 0,16,32,48
    const unsigned short* ag = A  + (size_t)(m0 + sr) * K + sc;
    const unsigned short* bg = Bm + (size_t)(n0 + sr) * K + sc;

    for (int k0 = 0; k0 < K; k0 += 64) {
        int4 av0 = *reinterpret_cast<const int4*>(ag + k0);
        int4 av1 = *reinterpret_cast<const int4*>(ag + k0 + 8);
        int4 bv0 = *reinterpret_cast<const int4*>(bg + k0);
        int4 bv1 = *reinterpret_cast<const int4*>(bg + k0 + 8);
        __syncthreads();   // prev-iter reads done before overwrite
        *reinterpret_cast<int4*>(&As[sr][sc])     = av0;
        *reinterpret_cast<int4*>(&As[sr][sc + 8]) = av1;
        *reinterpret_cast<int4*>(&Bs[sr][sc])     = bv0;
        *reinterpret_cast<int4*>(&Bs[sr][sc + 8]) = bv1;
        __syncthreads();
        #pragma unroll
        for (int kk = 0; kk < 2; ++kk) {
            bf16x8 af[2], bf[2];
            #pragma unroll
            for (int mi = 0; mi < 2; ++mi)
                af[mi] = *reinterpret_cast<const bf16x8*>(&As[wm*32 + mi*16 + l15][kk*32 + l4*8]);
            #pragma unroll
            for (int ni = 0; ni < 2; ++ni)
                bf[ni] = *reinterpret_cast<const bf16x8*>(&Bs[wn*32 + ni*16 + l15][kk*32 + l4*8]);
            #pragma unroll
            for (int mi = 0; mi < 2; ++mi)
                #pragma unroll
                for (int ni = 0; ni < 2; ++ni)
                    acc[mi][ni] = __builtin_amdgcn_mfma_f32_16x16x32_bf16(
                        af[mi], bf[ni], acc[mi][ni], 0, 0, 0);
        }
    }

    #pragma unroll
    for (int mi = 0; mi < 2; ++mi) {
        #pragma unroll
        for (int ni = 0; ni < 2; ++ni) {
            const int colg = n0 + wn*32 + ni*16 + l15;
            const float bv = bias[colg];
            #pragma unroll
            for (int j = 0; j < 4; ++j) {
                const int rowg = m0 + wm*32 + mi*16 + l4*4 + j;
                float v = acc[mi][ni][j] + bv;
                if constexpr (sizeof(OutT) == 2) {
                    C[(size_t)rowg * N + colg] = (OutT)f2bf(v);
                } else {
                    C[(size_t)rowg * N + colg] = v;
                }
            }
        }
    }
}

// ---------------- flash attention (causal) ----------------
// grid: (S/64, H, B); block 256 = 4 waves, each wave owns 16 q rows.
__global__ __launch_bounds__(256) void attn_kernel(
    const unsigned short* __restrict__ qb,
    const unsigned short* __restrict__ kb,
    const unsigned short* __restrict__ vb,
    unsigned short* __restrict__ yb)
{
    __shared__ unsigned short Klds[32][80];       // 160B stride
    __shared__ unsigned short Vlds[32][80];
    __shared__ unsigned short Plds[4][16][40];    // per-wave P tile, 80B stride

    const int tid  = threadIdx.x;
    const int lane = tid & 63, w = tid >> 6;
    const int l15  = lane & 15, l4 = lane >> 4;
    const int qt = blockIdx.x, h = blockIdx.y, b = blockIdx.z;
    const int q0  = qt * 64;
    const int q0w = q0 + w * 16;
    const size_t baseTok = (size_t)b * S_;

    // Q fragments: rows q0w..q0w+15, hd = 64 (two K=32 halves)
    bf16x8 qf[2];
    {
        const unsigned short* qp = qb + (baseTok + q0w + l15) * D_ + h * HD_ + l4 * 8;
        qf[0] = *reinterpret_cast<const bf16x8*>(qp);
        qf[1] = *reinterpret_cast<const bf16x8*>(qp + 32);
    }

    f32x4 o_acc[4] = {};
    float m_run[4] = {-INFINITY, -INFINITY, -INFINITY, -INFINITY};
    float l_run[4] = {0.f, 0.f, 0.f, 0.f};

    const int sr  = tid >> 3;         // 0..31
    const int scc = (tid & 7) << 3;   // 0..56
    const unsigned short* kg = kb + (baseTok + sr) * D_ + h * HD_ + scc;
    const unsigned short* vg = vb + (baseTok + sr) * D_ + h * HD_ + scc;

    const int nkv = 2 * qt + 2;
    for (int t = 0; t < nkv; ++t) {
        const int kv0 = t * 32;
        int4 kvk = *reinterpret_cast<const int4*>(kg + (size_t)kv0 * D_);
        int4 kvv = *reinterpret_cast<const int4*>(vg + (size_t)kv0 * D_);
        __syncthreads();
        *reinterpret_cast<int4*>(&Klds[sr][scc]) = kvk;
        *reinterpret_cast<int4*>(&Vlds[sr][scc]) = kvv;
        __syncthreads();

        if (kv0 <= q0w + 15) {
            // ---- S = Q K^T ----
            f32x4 s0 = {0.f,0.f,0.f,0.f}, s1 = {0.f,0.f,0.f,0.f};
            #pragma unroll
            for (int kh = 0; kh < 2; ++kh) {
                bf16x8 k0f = *reinterpret_cast<const bf16x8*>(&Klds[l15][kh*32 + l4*8]);
                bf16x8 k1f = *reinterpret_cast<const bf16x8*>(&Klds[16 + l15][kh*32 + l4*8]);
                s0 = __builtin_amdgcn_mfma_f32_16x16x32_bf16(qf[kh], k0f, s0, 0, 0, 0);
                s1 = __builtin_amdgcn_mfma_f32_16x16x32_bf16(qf[kh], k1f, s1, 0, 0, 0);
            }

            const bool need_mask = (kv0 + 31 > q0w);
            #pragma unroll
            for (int j = 0; j < 4; ++j) {
                float v0 = s0[j] * 0.03125f;   // 1/sqrt(1024)
                float v1 = s1[j] * 0.03125f;
                const int rowg = q0w + l4*4 + j;
                if (need_mask) {
                    if (kv0 + l15 > rowg)      v0 = -INFINITY;
                    if (kv0 + 16 + l15 > rowg) v1 = -INFINITY;
                }
                float mt = fmaxf(v0, v1);
                mt = fmaxf(mt, __shfl_xor(mt, 1));
                mt = fmaxf(mt, __shfl_xor(mt, 2));
                mt = fmaxf(mt, __shfl_xor(mt, 4));
                mt = fmaxf(mt, __shfl_xor(mt, 8));
                const float mnew  = fmaxf(m_run[j], mt);
                const float alpha = __expf(m_run[j] - mnew);  // 0 on first tile
                const float p0 = __expf(v0 - mnew);
                const float p1 = __expf(v1 - mnew);
                float ps = p0 + p1;
                ps += __shfl_xor(ps, 1);
                ps += __shfl_xor(ps, 2);
                ps += __shfl_xor(ps, 4);
                ps += __shfl_xor(ps, 8);
                l_run[j] = l_run[j] * alpha + ps;
                m_run[j] = mnew;
                #pragma unroll
                for (int nb = 0; nb < 4; ++nb) o_acc[nb][j] *= alpha;
                Plds[w][l4*4 + j][l15]      = f2bf(p0);
                Plds[w][l4*4 + j][16 + l15] = f2bf(p1);
            }

            // ---- O += P V ----
            bf16x8 pf = *reinterpret_cast<const bf16x8*>(&Plds[w][l15][l4*8]);
            #pragma unroll
            for (int nb = 0; nb < 4; ++nb) {
                us8 vv;
                #pragma unroll
                for (int jj = 0; jj < 8; ++jj)
                    vv[jj] = Vlds[l4*8 + jj][nb*16 + l15];
                bf16x8 vfr = __builtin_bit_cast(bf16x8, vv);
                o_acc[nb] = __builtin_amdgcn_mfma_f32_16x16x32_bf16(pf, vfr, o_acc[nb], 0, 0, 0);
            }
        }
    }

    // epilogue: normalize + store
    #pragma unroll
    for (int j = 0; j < 4; ++j) {
        const float inv = 1.0f / l_run[j];
        const int rowg = q0w + l4*4 + j;
        unsigned short* yp = yb + (baseTok + rowg) * D_ + h * HD_ + l15;
        #pragma unroll
        for (int nb = 0; nb < 4; ++nb)
            yp[nb * 16] = f2bf(o_acc[nb][j] * inv);
    }
}

// ---------------- launch ----------------
extern "C" void kernel_launch(void* const* d_in, const int* in_sizes, int n_in,
                              void* d_out, int out_size, void* d_ws, size_t ws_size,
                              hipStream_t stream)
{
    const float* x  = (const float*)d_in[0];
    const float* Wq = (const float*)d_in[1];
    const float* bq = (const float*)d_in[2];
    const float* Wk = (const float*)d_in[3];
    const float* bk = (const float*)d_in[4];
    const float* Wv = (const float*)d_in[5];
    const float* bv = (const float*)d_in[6];
    const float* Wp = (const float*)d_in[7];
    const float* bp = (const float*)d_in[8];

    char* ws = (char*)d_ws;
    const size_t SZ_X = (size_t)B_ * S_ * D_ * 2;   // 8 MB bf16
    const size_t SZ_W = (size_t)D_ * D_ * 2;        // 2 MB bf16
    unsigned short* xb  = (unsigned short*)(ws);
    unsigned short* wqb = (unsigned short*)(ws + SZ_X);
    unsigned short* wkb = (unsigned short*)(ws + SZ_X + SZ_W);
    unsigned short* wvb = (unsigned short*)(ws + SZ_X + 2*SZ_W);
    unsigned short* wpb = (unsigned short*)(ws + SZ_X + 3*SZ_W);
    unsigned short* qbuf = (unsigned short*)(ws + SZ_X + 4*SZ_W);
    unsigned short* kbuf = (unsigned short*)(ws + 2*SZ_X + 4*SZ_W);
    unsigned short* vbuf = (unsigned short*)(ws + 3*SZ_X + 4*SZ_W);
    unsigned short* ybuf = (unsigned short*)(ws + 4*SZ_X + 4*SZ_W);

    const int M = B_ * S_;   // 4096
    const int NX = B_ * S_ * D_;   // 4194304
    const int NW = D_ * D_;        // 1048576

    cvt_f32_bf16<<<NX / 1024, 256, 0, stream>>>(x,  xb,  NX);
    cvt_f32_bf16<<<NW / 1024, 256, 0, stream>>>(Wq, wqb, NW);
    cvt_f32_bf16<<<NW / 1024, 256, 0, stream>>>(Wk, wkb, NW);
    cvt_f32_bf16<<<NW / 1024, 256, 0, stream>>>(Wv, wvb, NW);
    cvt_f32_bf16<<<NW / 1024, 256, 0, stream>>>(Wp, wpb, NW);

    dim3 ggrid(M / 64, D_ / 64, 1);
    gemm_bt<unsigned short><<<ggrid, 256, 0, stream>>>(xb, wqb, bq, qbuf, M, D_, D_);
    gemm_bt<unsigned short><<<ggrid, 256, 0, stream>>>(xb, wkb, bk, kbuf, M, D_, D_);
    gemm_bt<unsigned short><<<ggrid, 256, 0, stream>>>(xb, wvb, bv, vbuf, M, D_, D_);

    attn_kernel<<<dim3(S_ / 64, H_, B_), 256, 0, stream>>>(qbuf, kbuf, vbuf, ybuf);

    gemm_bt<float><<<ggrid, 256, 0, stream>>>(ybuf, wpb, bp, (float*)d_out, M, D_, D_);
}

// Round 2
// 312.967 us; speedup vs baseline: 1.1654x; 1.1654x over previous
//
#include <hip/hip_runtime.h>
#include <hip/hip_bf16.h>

#define B_  2
#define S_  2048
#define D_  1024
#define H_  16
#define HD_ 64

typedef float  f32x4 __attribute__((ext_vector_type(4)));
typedef __bf16 bf16x8 __attribute__((ext_vector_type(8)));

__device__ __forceinline__ unsigned short f2bf(float f) {
    union { float f; unsigned int u; } x; x.f = f;
    unsigned int u = x.u;
    unsigned int r = (u + 0x7FFFu + ((u >> 16) & 1u)) >> 16;
    return (unsigned short)r;
}

__device__ __forceinline__ void gload_lds16(const unsigned short* g, unsigned short* l) {
    __builtin_amdgcn_global_load_lds(
        (const __attribute__((address_space(1))) unsigned int*)g,
        (__attribute__((address_space(3))) unsigned int*)l, 16, 0, 0);
}

// ---------------- fp32 -> bf16 convert ----------------
__global__ __launch_bounds__(256) void cvt_f32_bf16(
    const float* __restrict__ src, unsigned short* __restrict__ dst, int n)
{
    int i = (blockIdx.x * 256 + threadIdx.x) * 4;
    if (i < n) {
        float4 v = *reinterpret_cast<const float4*>(src + i);
        ushort4 o;
        o.x = f2bf(v.x); o.y = f2bf(v.y); o.z = f2bf(v.z); o.w = f2bf(v.w);
        *reinterpret_cast<ushort4*>(dst + i) = o;
    }
}

// ---------------- GEMM: C[m][n] = sum_k A[m,k]*B[n,k] + bias[n] ----------------
// 128x64 tile, 4 waves (each 64x32), BK=64, global_load_lds staging.
// OUT_MODE: 0 = fp32, 1 = bf16, 2 = bf16 transposed per-head (V^T [b][h][hd][S])
template <int OUT_MODE>
__global__ __launch_bounds__(256, 2) void gemm_bt128(
    const unsigned short* __restrict__ A,
    const unsigned short* __restrict__ Bm,
    const float* __restrict__ bias,
    void* __restrict__ Cout,
    int M, int N, int K)
{
    __shared__ unsigned short As[128 * 64];   // linear row-major [128][64]
    __shared__ unsigned short Bs[64 * 64];
    const int tid  = threadIdx.x;
    const int lane = tid & 63;
    const int w    = tid >> 6;
    const int wm   = w >> 1, wn = w & 1;
    const int m0   = blockIdx.x << 7;
    const int n0   = blockIdx.y << 6;
    const int l15  = lane & 15, l4 = lane >> 4;
    const int crow = lane >> 3;            // 0..7 row within 8-row chunk
    const int ccol = (lane & 7) << 3;      // us col 0..56

    f32x4 acc[4][2] = {};

    for (int k0 = 0; k0 < K; k0 += 64) {
        if (k0) __syncthreads();           // prev-iter LDS reads done
        #pragma unroll
        for (int i = 0; i < 6; ++i) {      // 24 chunks of 1KB: 0..15 A, 16..23 B
            const int c = w * 6 + i;
            if (c < 16) {
                const unsigned short* gp = A + (size_t)(m0 + c * 8 + crow) * K + k0 + ccol;
                gload_lds16(gp, As + c * 512);
            } else {
                const unsigned short* gp = Bm + (size_t)(n0 + (c - 16) * 8 + crow) * K + k0 + ccol;
                gload_lds16(gp, Bs + (c - 16) * 512);
            }
        }
        __syncthreads();                   // compiler drains vmcnt before barrier
        #pragma unroll
        for (int kk = 0; kk < 2; ++kk) {
            bf16x8 af[4], bf[2];
            #pragma unroll
            for (int mi = 0; mi < 4; ++mi)
                af[mi] = *reinterpret_cast<const bf16x8*>(&As[(wm * 64 + mi * 16 + l15) * 64 + kk * 32 + l4 * 8]);
            #pragma unroll
            for (int ni = 0; ni < 2; ++ni)
                bf[ni] = *reinterpret_cast<const bf16x8*>(&Bs[(wn * 32 + ni * 16 + l15) * 64 + kk * 32 + l4 * 8]);
            #pragma unroll
            for (int mi = 0; mi < 4; ++mi)
                #pragma unroll
                for (int ni = 0; ni < 2; ++ni)
                    acc[mi][ni] = __builtin_amdgcn_mfma_f32_16x16x32_bf16(af[mi], bf[ni], acc[mi][ni], 0, 0, 0);
        }
    }

    #pragma unroll
    for (int mi = 0; mi < 4; ++mi) {
        #pragma unroll
        for (int ni = 0; ni < 2; ++ni) {
            const int colg = n0 + wn * 32 + ni * 16 + l15;
            const float bv = bias[colg];
            const int rowb = m0 + wm * 64 + mi * 16 + l4 * 4;
            if constexpr (OUT_MODE == 0) {
                float* C = (float*)Cout;
                #pragma unroll
                for (int j = 0; j < 4; ++j)
                    C[(size_t)(rowb + j) * N + colg] = acc[mi][ni][j] + bv;
            } else if constexpr (OUT_MODE == 1) {
                unsigned short* C = (unsigned short*)Cout;
                #pragma unroll
                for (int j = 0; j < 4; ++j)
                    C[(size_t)(rowb + j) * N + colg] = f2bf(acc[mi][ni][j] + bv);
            } else {
                // V^T: vt[(b*H + h)*HD*S + hd*S + s], 4 consecutive s -> 8B store
                ushort4 pk;
                pk.x = f2bf(acc[mi][ni][0] + bv);
                pk.y = f2bf(acc[mi][ni][1] + bv);
                pk.z = f2bf(acc[mi][ni][2] + bv);
                pk.w = f2bf(acc[mi][ni][3] + bv);
                const int bb = rowb >> 11, s = rowb & (S_ - 1);
                unsigned short* vt = (unsigned short*)Cout +
                    ((size_t)(bb * H_ + (colg >> 6)) * HD_ + (colg & 63)) * S_ + s;
                *reinterpret_cast<ushort4*>(vt) = pk;
            }
        }
    }
}

// ---------------- flash attention v2 (causal, no K/V LDS staging) ----------------
// grid: (S/128, H, B); block 256 = 4 waves, each wave owns 32 q rows, KV tile 64.
__global__ __launch_bounds__(256, 2) void attn2(
    const unsigned short* __restrict__ qb,
    const unsigned short* __restrict__ kb,
    const unsigned short* __restrict__ vt,
    unsigned short* __restrict__ yb)
{
    __shared__ unsigned short Plds[4][32][72];   // per-wave P tile, 144B stride (2-way = free)

    const int tid  = threadIdx.x;
    const int lane = tid & 63, w = tid >> 6;
    const int l15  = lane & 15, l4 = lane >> 4;
    const int qt   = gridDim.x - 1 - blockIdx.x;   // heavy tiles first
    const int h    = blockIdx.y, b = blockIdx.z;
    const int q0w  = qt * 128 + w * 32;
    const size_t baseTok = (size_t)b * S_;
    const unsigned short* kgh = kb + baseTok * D_ + h * HD_;
    const unsigned short* vth = vt + (size_t)(b * H_ + h) * HD_ * S_;

    bf16x8 qf[2][2];
    #pragma unroll
    for (int m = 0; m < 2; ++m)
        #pragma unroll
        for (int kh = 0; kh < 2; ++kh)
            qf[m][kh] = *reinterpret_cast<const bf16x8*>(
                qb + (baseTok + q0w + m * 16 + l15) * D_ + h * HD_ + kh * 32 + l4 * 8);

    f32x4 o_acc[2][4] = {};
    float m_run[2][4] = {{-INFINITY,-INFINITY,-INFINITY,-INFINITY},
                         {-INFINITY,-INFINITY,-INFINITY,-INFINITY}};
    float l_part[2][4] = {};

    const int nkv = (q0w + 95) >> 6;   // kv tiles of 64 covering kv <= q0w+31
    for (int t = 0; t < nkv; ++t) {
        const int kv0 = t << 6;
        // K fragments: global -> reg (L2-resident, shared across q-blocks)
        bf16x8 kf[4][2];
        #pragma unroll
        for (int kvb = 0; kvb < 4; ++kvb)
            #pragma unroll
            for (int kh = 0; kh < 2; ++kh)
                kf[kvb][kh] = *reinterpret_cast<const bf16x8*>(
                    kgh + (size_t)(kv0 + kvb * 16 + l15) * D_ + kh * 32 + l4 * 8);

        const bool need_mask = (kv0 + 63 > q0w);
        #pragma unroll
        for (int m = 0; m < 2; ++m) {
            f32x4 s[4] = {};
            #pragma unroll
            for (int kvb = 0; kvb < 4; ++kvb)
                #pragma unroll
                for (int kh = 0; kh < 2; ++kh)
                    s[kvb] = __builtin_amdgcn_mfma_f32_16x16x32_bf16(qf[m][kh], kf[kvb][kh], s[kvb], 0, 0, 0);

            #pragma unroll
            for (int j = 0; j < 4; ++j) {
                const int rowg = q0w + m * 16 + l4 * 4 + j;
                float v[4];
                #pragma unroll
                for (int kvb = 0; kvb < 4; ++kvb) {
                    v[kvb] = s[kvb][j] * 0.03125f;   // 1/sqrt(1024)
                    if (need_mask && (kv0 + kvb * 16 + l15 > rowg)) v[kvb] = -INFINITY;
                }
                float mt = fmaxf(fmaxf(v[0], v[1]), fmaxf(v[2], v[3]));
                mt = fmaxf(mt, __shfl_xor(mt, 1));
                mt = fmaxf(mt, __shfl_xor(mt, 2));
                mt = fmaxf(mt, __shfl_xor(mt, 4));
                mt = fmaxf(mt, __shfl_xor(mt, 8));
                const float mnew  = fmaxf(m_run[m][j], mt);
                const float alpha = __expf(m_run[m][j] - mnew);
                m_run[m][j] = mnew;
                float ps = 0.f;
                #pragma unroll
                for (int kvb = 0; kvb < 4; ++kvb) {
                    const float p = __expf(v[kvb] - mnew);
                    ps += p;
                    Plds[w][m * 16 + l4 * 4 + j][kvb * 16 + l15] = f2bf(p);
                }
                l_part[m][j] = l_part[m][j] * alpha + ps;   // lane-partial, reduced at end
                #pragma unroll
                for (int nb = 0; nb < 4; ++nb) o_acc[m][nb][j] *= alpha;
            }
        }

        // ---- O += P V : V^T fragments direct from global ----
        #pragma unroll
        for (int kvh = 0; kvh < 2; ++kvh) {
            bf16x8 vf[4];
            #pragma unroll
            for (int nb = 0; nb < 4; ++nb)
                vf[nb] = *reinterpret_cast<const bf16x8*>(
                    vth + (size_t)(nb * 16 + l15) * S_ + kv0 + kvh * 32 + l4 * 8);
            #pragma unroll
            for (int m = 0; m < 2; ++m) {
                bf16x8 pf = *reinterpret_cast<const bf16x8*>(&Plds[w][m * 16 + l15][kvh * 32 + l4 * 8]);
                #pragma unroll
                for (int nb = 0; nb < 4; ++nb)
                    o_acc[m][nb] = __builtin_amdgcn_mfma_f32_16x16x32_bf16(pf, vf[nb], o_acc[m][nb], 0, 0, 0);
            }
        }
    }

    // epilogue: reduce lane-partial row sums, normalize, store
    #pragma unroll
    for (int m = 0; m < 2; ++m) {
        #pragma unroll
        for (int j = 0; j < 4; ++j) {
            float l = l_part[m][j];
            l += __shfl_xor(l, 1);
            l += __shfl_xor(l, 2);
            l += __shfl_xor(l, 4);
            l += __shfl_xor(l, 8);
            const float inv = 1.0f / l;
            const int rowg = q0w + m * 16 + l4 * 4 + j;
            unsigned short* yp = yb + (baseTok + rowg) * D_ + h * HD_ + l15;
            #pragma unroll
            for (int nb = 0; nb < 4; ++nb)
                yp[nb * 16] = f2bf(o_acc[m][nb][j] * inv);
        }
    }
}

// ---------------- launch ----------------
extern "C" void kernel_launch(void* const* d_in, const int* in_sizes, int n_in,
                              void* d_out, int out_size, void* d_ws, size_t ws_size,
                              hipStream_t stream)
{
    const float* x  = (const float*)d_in[0];
    const float* Wq = (const float*)d_in[1];
    const float* bq = (const float*)d_in[2];
    const float* Wk = (const float*)d_in[3];
    const float* bk = (const float*)d_in[4];
    const float* Wv = (const float*)d_in[5];
    const float* bv = (const float*)d_in[6];
    const float* Wp = (const float*)d_in[7];
    const float* bp = (const float*)d_in[8];

    char* ws = (char*)d_ws;
    const size_t SZ_X = (size_t)B_ * S_ * D_ * 2;   // 8 MB bf16
    const size_t SZ_W = (size_t)D_ * D_ * 2;        // 2 MB bf16
    unsigned short* xb   = (unsigned short*)(ws);
    unsigned short* wqb  = (unsigned short*)(ws + SZ_X);
    unsigned short* wkb  = (unsigned short*)(ws + SZ_X + SZ_W);
    unsigned short* wvb  = (unsigned short*)(ws + SZ_X + 2 * SZ_W);
    unsigned short* wpb  = (unsigned short*)(ws + SZ_X + 3 * SZ_W);
    unsigned short* qbuf = (unsigned short*)(ws + SZ_X + 4 * SZ_W);
    unsigned short* kbuf = (unsigned short*)(ws + 2 * SZ_X + 4 * SZ_W);
    unsigned short* vtbf = (unsigned short*)(ws + 3 * SZ_X + 4 * SZ_W);
    unsigned short* ybuf = (unsigned short*)(ws + 4 * SZ_X + 4 * SZ_W);

    const int M  = B_ * S_;          // 4096
    const int NX = B_ * S_ * D_;
    const int NW = D_ * D_;

    cvt_f32_bf16<<<NX / 1024, 256, 0, stream>>>(x,  xb,  NX);
    cvt_f32_bf16<<<NW / 1024, 256, 0, stream>>>(Wq, wqb, NW);
    cvt_f32_bf16<<<NW / 1024, 256, 0, stream>>>(Wk, wkb, NW);
    cvt_f32_bf16<<<NW / 1024, 256, 0, stream>>>(Wv, wvb, NW);
    cvt_f32_bf16<<<NW / 1024, 256, 0, stream>>>(Wp, wpb, NW);

    dim3 ggrid(M / 128, D_ / 64, 1);
    gemm_bt128<1><<<ggrid, 256, 0, stream>>>(xb, wqb, bq, qbuf, M, D_, D_);
    gemm_bt128<1><<<ggrid, 256, 0, stream>>>(xb, wkb, bk, kbuf, M, D_, D_);
    gemm_bt128<2><<<ggrid, 256, 0, stream>>>(xb, wvb, bv, vtbf, M, D_, D_);

    attn2<<<dim3(S_ / 128, H_, B_), 256, 0, stream>>>(qbuf, kbuf, vtbf, ybuf);

    gemm_bt128<0><<<ggrid, 256, 0, stream>>>(ybuf, wpb, bp, (float*)d_out, M, D_, D_);
}